// Round 20
// baseline (682.146 us; speedup 1.0000x reference)
//
#include <hip/hip_runtime.h>

typedef unsigned short u16;
typedef unsigned int   u32;
typedef __attribute__((ext_vector_type(4))) float f32x4;
typedef __attribute__((ext_vector_type(8))) __bf16 bf16x8;
typedef __attribute__((ext_vector_type(8))) unsigned short u16x8;

#define DEV __device__ __forceinline__

DEV u16 f2bf(float f){
  u32 u = __builtin_bit_cast(u32, f);
  u32 r = (u + 0x7fffu + ((u >> 16) & 1u)) >> 16;
  return (u16)r;
}
DEV float bf2f(u16 u){ u32 x = ((u32)u) << 16; return __builtin_bit_cast(float, x); }

DEV f32x4 mfma16(bf16x8 a, bf16x8 b, f32x4 c){
  return __builtin_amdgcn_mfma_f32_16x16x32_bf16(a, b, c, 0, 0, 0);
}

DEV void gload16(const void* g, void* l){
  __builtin_amdgcn_global_load_lds((const __attribute__((address_space(1))) u32*)g,
                                   (__attribute__((address_space(3))) u32*)l, 16, 0, 0);
}

// XOR swizzle for [row][64 bf16] LDS tiles (128B row stride), 16B-group granularity.
DEV int swz16(int r, int g){ return r*64 + 8*(g ^ (r&7) ^ ((r>>3)&7)); }
DEV int swze (int r, int e){ return r*64 + (e&7) + 8*(((e>>3) ^ (r&7) ^ ((r>>3)&7))); }

// ---------------- weight transpose + cast: src [R][C] f32 -> dst [C][R] bf16 ----------------
__global__ __launch_bounds__(256) void transpose_cast(const float* __restrict__ src,
                                                      u16* __restrict__ dst, int R, int C){
  __shared__ float tile[32][33];
  int r  = threadIdx.x >> 3;
  int c4 = (threadIdx.x & 7) * 4;
  int r0 = blockIdx.x * 32, c0 = blockIdx.y * 32;
  float4 v = *(const float4*)&src[(size_t)(r0 + r) * C + c0 + c4];
  tile[r][c4+0] = v.x; tile[r][c4+1] = v.y; tile[r][c4+2] = v.z; tile[r][c4+3] = v.w;
  __syncthreads();
  ushort4 o;
  o.x = f2bf(tile[c4+0][r]);
  o.y = f2bf(tile[c4+1][r]);
  o.z = f2bf(tile[c4+2][r]);
  o.w = f2bf(tile[c4+3][r]);
  *(ushort4*)&dst[(size_t)(c0 + r) * R + r0 + c4] = o;
}

// ---------------- inv rms per row (D=1024) ----------------
__global__ __launch_bounds__(256) void rms_inv_k(const float* __restrict__ x, float* __restrict__ inv){
  int row  = blockIdx.x * 4 + (threadIdx.x >> 6);
  int lane = threadIdx.x & 63;
  const float* p = x + (size_t)row * 1024;
  float ss = 0.f;
  #pragma unroll
  for (int j = 0; j < 4; ++j){
    float4 v = *(const float4*)&p[lane*4 + j*256];
    ss += v.x*v.x + v.y*v.y + v.z*v.z + v.w*v.w;
  }
  #pragma unroll
  for (int o = 1; o < 64; o <<= 1) ss += __shfl_xor(ss, o);
  if (lane == 0) inv[row] = 1.f / sqrtf(ss * (1.f/1024.f) + 1e-6f);
}

// ---------------- SSM chunked scan ----------------
__global__ __launch_bounds__(1024) void ssm_a_k(const float* __restrict__ hid, const float* __restrict__ invr,
    const float* __restrict__ nw, const float* __restrict__ av, float* __restrict__ Fc){
  int c = blockIdx.x & 63, b = blockIdx.x >> 6;
  int d = threadIdx.x;
  float w   = nw[d];
  float dec = 1.f/(1.f + expf(-av[d]));
  float od  = 1.f - dec;
  const float* hp = hid + ((size_t)b*4096 + c*64)*1024 + d;
  const float* ip = invr + b*4096 + c*64;
  float hs = 0.f;
  for (int i = 0; i < 64; ++i)
    hs = dec*hs + od*(hp[(size_t)i*1024] * ip[i] * w);
  Fc[((size_t)b*64 + c)*1024 + d] = hs;
}
// parallel chunk-carry scan: wave-level Kogge-Stone over 64 chunks
__global__ __launch_bounds__(1024) void ssm_b_k(const float* __restrict__ Fc, float* __restrict__ Init,
                                                const float* __restrict__ av){
  int b  = blockIdx.x >> 6;
  int dg = blockIdx.x & 63;
  int dl = threadIdx.x >> 6;
  int c  = threadIdx.x & 63;
  int d  = dg*16 + dl;
  float dec = 1.f/(1.f + expf(-av[d]));
  float a = powf(dec, 64.f);
  float x = Fc[((size_t)(b*64 + c))*1024 + d];
  float coef = a;
  #pragma unroll
  for (int s = 1; s < 64; s <<= 1){
    float prev = __shfl_up(x, s, 64);
    if (c >= s) x += coef * prev;
    coef *= coef;
  }
  float ex = __shfl_up(x, 1, 64);
  Init[((size_t)(b*64 + c))*1024 + d] = (c > 0) ? ex : 0.f;
}
__global__ __launch_bounds__(1024) void ssm_c_k(const float* __restrict__ hid, const float* __restrict__ invr,
    const float* __restrict__ nw, const float* __restrict__ av, const float* __restrict__ gn,
    const float* __restrict__ Init, float* __restrict__ hout){
  int c = blockIdx.x & 63, b = blockIdx.x >> 6;
  int d = threadIdx.x;
  float w   = nw[d];
  float g   = gn[d];
  float dec = 1.f/(1.f + expf(-av[d]));
  float od  = 1.f - dec;
  size_t rowoff = ((size_t)b*4096 + c*64)*1024 + d;
  const float* hp = hid + rowoff;
  float* op = hout + rowoff;
  const float* ip = invr + b*4096 + c*64;
  float hs = Init[((size_t)b*64 + c)*1024 + d];
  for (int i = 0; i < 64; ++i){
    float hv = hp[(size_t)i*1024];
    hs = dec*hs + od*(hv * ip[i] * w);
    op[(size_t)i*1024] = hv + hs*g;
  }
}

// ---------------- router scores ----------------
__global__ __launch_bounds__(256) void score_k(const float* __restrict__ h, const float* __restrict__ rw,
                                               float* __restrict__ sc){
  int row  = blockIdx.x * 4 + (threadIdx.x >> 6);
  int lane = threadIdx.x & 63;
  const float* p = h + (size_t)row * 1024;
  float s = 0.f;
  #pragma unroll
  for (int j = 0; j < 4; ++j){
    float4 v = *(const float4*)&p[lane*4 + j*256];
    float4 w = *(const float4*)&rw[lane*4 + j*256];
    s += v.x*w.x + v.y*w.y + v.z*w.z + v.w*w.w;
  }
  #pragma unroll
  for (int o = 1; o < 64; o <<= 1) s += __shfl_xor(s, o);
  if (lane == 0) sc[row] = s;
}

__global__ __launch_bounds__(256) void aux_k(const float* __restrict__ sc, float* __restrict__ out){
  __shared__ float red[256];
  int tid = threadIdx.x;
  float s = 0.f;
  for (int i = tid; i < 16384; i += 256) s += 1.f/(1.f + expf(-sc[i]));
  red[tid] = s; __syncthreads();
  for (int o = 128; o > 0; o >>= 1){ if (tid < o) red[tid] += red[tid+o]; __syncthreads(); }
  if (tid == 0) out[0] = red[0] * (1.f/16384.f);
}

// ---------------- top-k via radix select + stable compaction (per batch) ----------------
__global__ __launch_bounds__(1024) void topk_k(const float* __restrict__ sc, int* __restrict__ idx,
                                               float* __restrict__ wsel){
  __shared__ u32 keys[4096];
  __shared__ int hist[256];
  __shared__ int wsum[16];
  __shared__ int sel_info[2];
  int b = blockIdx.x, tid = threadIdx.x;
  for (int i = tid; i < 4096; i += 1024){
    u32 u = __builtin_bit_cast(u32, sc[b*4096 + i]);
    keys[i] = u ^ ((u32)((int)u >> 31) | 0x80000000u);   // order-preserving map
  }
  int k = 1024;
  u32 prefix = 0, mask = 0;
  for (int level = 3; level >= 0; --level){
    __syncthreads();
    if (tid < 256) hist[tid] = 0;
    __syncthreads();
    int sh = level*8;
    for (int i = tid; i < 4096; i += 1024){
      u32 kk = keys[i];
      if ((kk & mask) == prefix) atomicAdd(&hist[(kk >> sh) & 255], 1);
    }
    __syncthreads();
    if (tid == 0){
      int cum = 0, bb = 255;
      for (; bb > 0; --bb){
        if (cum + hist[bb] >= k) break;
        cum += hist[bb];
      }
      sel_info[0] = bb; sel_info[1] = k - cum;
    }
    __syncthreads();
    prefix |= ((u32)sel_info[0]) << sh;
    mask |= 0xffu << sh;
    k = sel_info[1];
  }
  u32 T = prefix;
  // stable compaction: 4 elements/thread, packed block scan (gt | eq<<13)
  int base = tid*4;
  u32 k4[4]; int cgt = 0, ceq = 0;
  #pragma unroll
  for (int j = 0; j < 4; ++j){
    k4[j] = keys[base+j];
    cgt += (k4[j] > T); ceq += (k4[j] == T);
  }
  int val = cgt | (ceq << 13);
  int incl = val;
  #pragma unroll
  for (int o = 1; o < 64; o <<= 1){ int t = __shfl_up(incl, o, 64); if ((tid&63) >= o) incl += t; }
  int wid = tid >> 6;
  if ((tid&63) == 63) wsum[wid] = incl;
  __syncthreads();
  if (tid < 16){
    int v = wsum[tid];
    #pragma unroll
    for (int o = 1; o < 16; o <<= 1){ int t = __shfl_up(v, o, 64); if (tid >= o) v += t; }
    wsum[tid] = v;
  }
  __syncthreads();
  int excl = incl - val + (wid > 0 ? wsum[wid-1] : 0);
  int g = excl & 0x1fff, e = excl >> 13;
  #pragma unroll
  for (int j = 0; j < 4; ++j){
    bool isgt = (k4[j] > T), iseq = (k4[j] == T);
    if (isgt || (iseq && e < k)){
      int pos = g + (e < k ? e : k);
      idx[b*1024 + pos]  = base + j;
      wsel[b*1024 + pos] = 1.f/(1.f + expf(-sc[b*4096 + base + j]));
    }
    g += isgt; e += iseq;
  }
}

// ---------------- rmsnorm row -> bf16 (optional gather) ----------------
__global__ __launch_bounds__(256) void rownorm_bf16_k(const float* __restrict__ src, const float* __restrict__ w,
    u16* __restrict__ dst, const int* __restrict__ gidx, int base){
  int row  = blockIdx.x * 4 + (threadIdx.x >> 6);
  int lane = threadIdx.x & 63;
  size_t srow;
  if (gidx){ int b = row >> 10; srow = (size_t)b*4096 + gidx[row]; }
  else srow = (size_t)(base + row);
  const float* p = src + srow*1024;
  float4 v[4]; float ss = 0.f;
  #pragma unroll
  for (int j = 0; j < 4; ++j){
    v[j] = *(const float4*)&p[lane*4 + j*256];
    ss += v[j].x*v[j].x + v[j].y*v[j].y + v[j].z*v[j].z + v[j].w*v[j].w;
  }
  #pragma unroll
  for (int o = 1; o < 64; o <<= 1) ss += __shfl_xor(ss, o);
  float inv = 1.f / sqrtf(ss * (1.f/1024.f) + 1e-6f);
  #pragma unroll
  for (int j = 0; j < 4; ++j){
    float4 wv = *(const float4*)&w[lane*4 + j*256];
    ushort4 o4;
    o4.x = f2bf(v[j].x*inv*wv.x);
    o4.y = f2bf(v[j].y*inv*wv.y);
    o4.z = f2bf(v[j].z*inv*wv.z);
    o4.w = f2bf(v[j].w*inv*wv.w);
    *(ushort4*)&dst[(size_t)row*1024 + lane*4 + j*256] = o4;
  }
}

// ---------------- split-K reduce: h += p0 + p1 (bf16 partials, vectorized) ----------------
__global__ __launch_bounds__(256) void reduce2_k(const u16* __restrict__ p, float* __restrict__ h){
  int i = (blockIdx.x*256 + threadIdx.x) * 8;
  u16x8 a = *(const u16x8*)&p[i];
  u16x8 b = *(const u16x8*)&p[4194304 + i];
  #pragma unroll
  for (int j = 0; j < 8; ++j) h[i+j] += bf2f(a[j]) + bf2f(b[j]);
}

// ---------------- gemmk: wide 2-phase GEMM, BK=32, 256 thr, 2x2 waves ----------
template<int BM, int BN, int EPI>
__global__ __launch_bounds__(256, 4) void gemmk(const u16* __restrict__ A, const u16* __restrict__ BT,
    u16* __restrict__ Cb, float* __restrict__ Cf, int M, int N, int K,
    const int* __restrict__ gidx, const float* __restrict__ wsel){
  constexpr int WROWS = BM / 2;
  constexpr int WCOLS = BN / 2;
  constexpr int MI = WROWS / 16;
  constexpr int NI = WCOLS / 16;
  constexpr int AR = BM / 64;
  constexpr int BR = BN / 64;
  constexpr int STGB = 128*(BM+BN);
  constexpr int CSB  = BM*BN*2;
  constexpr int SMB  = STGB > CSB ? STGB : CSB;
  __shared__ __align__(16) char smem[SMB];
  u16* As = (u16*)smem;                 // [2][BM*32]
  u16* Bs = (u16*)(smem + 128*BM);      // [2][BN*32]

  int tid = threadIdx.x, wave = tid >> 6, lane = tid & 63;
  int lr = lane & 15, lg = lane >> 4;
  int wm = wave >> 1, wn = wave & 1;

  // bijective XCD swizzle, then 16x8 supertile decode
  int lin = blockIdx.x + gridDim.x * blockIdx.y;
  int nwg = gridDim.x * gridDim.y;
  int q8 = nwg >> 3, r8 = nwg & 7;
  int xc = lin & 7, of = lin >> 3;
  int sw = (xc < r8 ? xc*(q8+1) : r8*(q8+1) + (xc-r8)*q8) + of;
  int bm, bn;
  if ((gridDim.x & 15) == 0 && (gridDim.y & 7) == 0){
    int NSM = gridDim.x >> 4;
    int st = sw >> 7, wi = sw & 127;
    bm = (st % NSM)*16 + (wi & 15);
    bn = (st / NSM)*8  + (wi >> 4);
  } else { bm = sw % gridDim.x; bn = sw / gridDim.x; }

  f32x4 zero4 = {0.f,0.f,0.f,0.f};
  f32x4 acc[MI][NI];
  #pragma unroll
  for (int mi = 0; mi < MI; ++mi)
    #pragma unroll
    for (int ni = 0; ni < NI; ++ni) acc[mi][ni] = zero4;

  // staging: LDS[row][g'] = global[row][g' ^ ((row>>1)&3)]
  int srow = wave*16 + (lane >> 2);
  int sgrp = (lane & 3) ^ ((lane >> 3) & 3);
  const size_t Kb = (size_t)K * 2;
  const char* aptr[AR];
  const char* bptr[BR];
  #pragma unroll
  for (int rr = 0; rr < AR; ++rr)
    aptr[rr] = (const char*)A + (size_t)(bm*BM + rr*64 + srow) * Kb + sgrp*16;
  #pragma unroll
  for (int rr = 0; rr < BR; ++rr)
    bptr[rr] = (const char*)BT + (size_t)(bn*BN + rr*64 + srow) * Kb + sgrp*16;

  int nkt = K >> 5;

#define STAGE(T, BUF) do { \
    size_t koff = (size_t)(T) << 6; \
    _Pragma("unroll") \
    for (int rr = 0; rr < AR; ++rr) gload16(aptr[rr] + koff, (char*)As + (BUF)*BM*64 + rr*4096 + wave*1024); \
    _Pragma("unroll") \
    for (int rr = 0; rr < BR; ++rr) gload16(bptr[rr] + koff, (char*)Bs + (BUF)*BN*64 + rr*4096 + wave*1024); \
  } while(0)

  STAGE(0, 0);
  __syncthreads();

  #pragma unroll 2
  for (int kt = 0; kt < nkt; ++kt){
    int bi = kt & 1;
    if (kt + 1 < nkt) STAGE(kt+1, bi^1);

    bf16x8 bfrag[NI];
    #pragma unroll
    for (int ni = 0; ni < NI; ++ni){
      int row = wn*WCOLS + ni*16 + lr;
      bfrag[ni] = *(const bf16x8*)&Bs[bi*BN*32 + row*32 + ((lg ^ ((lr>>1) & 3))*8)];
    }
    bf16x8 afrag[MI];
    #pragma unroll
    for (int mi = 0; mi < MI; ++mi){
      int row = wm*WROWS + mi*16 + lr;
      afrag[mi] = *(const bf16x8*)&As[bi*BM*32 + row*32 + ((lg ^ ((lr>>1) & 3))*8)];
    }
    #pragma unroll
    for (int mi = 0; mi < MI; ++mi)
      #pragma unroll
      for (int ni = 0; ni < NI; ++ni)
        acc[mi][ni] = mfma16(afrag[mi], bfrag[ni], acc[mi][ni]);
    __syncthreads();
  }
#undef STAGE

  // LDS-staged coalesced epilogue (bf16 outputs)
  u16* Cs = (u16*)smem;
  #pragma unroll
  for (int mi = 0; mi < MI; ++mi){
    int rl = wm*WROWS + mi*16 + lg*4;
    #pragma unroll
    for (int ni = 0; ni < NI; ++ni){
      int cl = wn*WCOLS + ni*16 + lr;
      f32x4 v = acc[mi][ni];
      #pragma unroll
      for (int t = 0; t < 4; ++t){
        float x = v[t];
        if constexpr (EPI == 1) x = x / (1.f + expf(-x));
        Cs[(rl+t)*BN + cl] = f2bf(x);
      }
    }
  }
  __syncthreads();
  constexpr int TPR = BN*2/16;
  constexpr int RPI = 256 / TPR;
  int rloc = tid / TPR, cb = (tid % TPR)*16;
  #pragma unroll
  for (int r0 = 0; r0 < BM; r0 += RPI){
    int r = r0 + rloc;
    *(float4*)((char*)&Cb[(size_t)(bm*BM + r)*N + bn*BN] + cb) =
      *(const float4*)((const char*)&Cs[r*BN] + cb);
  }
  (void)Cf; (void)gidx; (void)wsel;
}

// ---------------- gemmks: split-K wide GEMM (gemm2 slices only) ----------------
template<int BM, int BN, int EPI>
__global__ __launch_bounds__(256, 3) void gemmks(const u16* __restrict__ A, const u16* __restrict__ BT,
    u16* __restrict__ Cb, float* __restrict__ Cf, int M, int N, int Ksl, int Kfull,
    const int* __restrict__ gidx, const float* __restrict__ wsel){
  constexpr int WROWS = BM / 2;
  constexpr int WCOLS = BN / 2;
  constexpr int MI = WROWS / 16;
  constexpr int NI = WCOLS / 16;
  constexpr int AR = BM / 64;
  constexpr int BR = BN / 64;
  constexpr int STGB = 128*(BM+BN);
  constexpr int CSB  = BM*BN*2;
  constexpr int SMB  = STGB > CSB ? STGB : CSB;
  __shared__ __align__(16) char smem[SMB];
  u16* As = (u16*)smem;                 // [2][BM*32]
  u16* Bs = (u16*)(smem + 128*BM);      // [2][BN*32]

  int tid = threadIdx.x, wave = tid >> 6, lane = tid & 63;
  int lr = lane & 15, lg = lane >> 4;
  int wm = wave >> 1, wn = wave & 1;

  int lin = blockIdx.x + gridDim.x * blockIdx.y;
  int nwg = gridDim.x * gridDim.y;
  int q8 = nwg >> 3, r8 = nwg & 7;
  int xc = lin & 7, of = lin >> 3;
  int sw = (xc < r8 ? xc*(q8+1) : r8*(q8+1) + (xc-r8)*q8) + of;
  int bm, bn;
  if ((gridDim.x & 15) == 0 && (gridDim.y & 7) == 0){
    int NSM = gridDim.x >> 4;
    int st = sw >> 7, wi = sw & 127;
    bm = (st % NSM)*16 + (wi & 15);
    bn = (st / NSM)*8  + (wi >> 4);
  } else { bm = sw % gridDim.x; bn = sw / gridDim.x; }

  f32x4 zero4 = {0.f,0.f,0.f,0.f};
  f32x4 acc[MI][NI];
  #pragma unroll
  for (int mi = 0; mi < MI; ++mi)
    #pragma unroll
    for (int ni = 0; ni < NI; ++ni) acc[mi][ni] = zero4;

  int srow = wave*16 + (lane >> 2);
  int sgrp = (lane & 3) ^ ((lane >> 3) & 3);
  const size_t Kb = (size_t)Kfull * 2;
  const size_t k0b = (size_t)blockIdx.z * Ksl * 2;
  const char* aptr[AR];
  const char* bptr[BR];
  #pragma unroll
  for (int rr = 0; rr < AR; ++rr)
    aptr[rr] = (const char*)A + (size_t)(bm*BM + rr*64 + srow) * Kb + k0b + sgrp*16;
  #pragma unroll
  for (int rr = 0; rr < BR; ++rr)
    bptr[rr] = (const char*)BT + (size_t)(bn*BN + rr*64 + srow) * Kb + k0b + sgrp*16;

  int nkt = Ksl >> 5;

#define STAGES(T, BUF) do { \
    size_t koff = (size_t)(T) << 6; \
    _Pragma("unroll") \
    for (int rr = 0; rr < AR; ++rr) gload16(aptr[rr] + koff, (char*)As + (BUF)*BM*64 + rr*4096 + wave*1024); \
    _Pragma("unroll") \
    for (int rr = 0; rr < BR; ++rr) gload16(bptr[rr] + koff, (char*)Bs + (BUF)*BN*64 + rr*4096 + wave*1024); \
  } while(0)

  STAGES(0, 0);
  __syncthreads();

  #pragma unroll 2
  for (int kt = 0; kt < nkt; ++kt){
    int bi = kt & 1;
    if (kt + 1 < nkt) STAGES(kt+1, bi^1);

    bf16x8 bfrag[NI];
    #pragma unroll
    for (int ni = 0; ni < NI; ++ni){
      int row = wn*WCOLS + ni*16 + lr;
      bfrag[ni] = *(const bf16x8*)&Bs[bi*BN*32 + row*32 + ((lg ^ ((lr>>1) & 3))*8)];
    }
    bf16x8 afrag[MI];
    #pragma unroll
    for (int mi = 0; mi < MI; ++mi){
      int row = wm*WROWS + mi*16 + lr;
      afrag[mi] = *(const bf16x8*)&As[bi*BM*32 + row*32 + ((lg ^ ((lr>>1) & 3))*8)];
    }
    #pragma unroll
    for (int mi = 0; mi < MI; ++mi)
      #pragma unroll
      for (int ni = 0; ni < NI; ++ni)
        acc[mi][ni] = mfma16(afrag[mi], bfrag[ni], acc[mi][ni]);
    __syncthreads();
  }
#undef STAGES

  u16* Cout = Cb + (size_t)blockIdx.z * M * N;
  u16* Cs = (u16*)smem;
  #pragma unroll
  for (int mi = 0; mi < MI; ++mi){
    int rl = wm*WROWS + mi*16 + lg*4;
    #pragma unroll
    for (int ni = 0; ni < NI; ++ni){
      int cl = wn*WCOLS + ni*16 + lr;
      f32x4 v = acc[mi][ni];
      #pragma unroll
      for (int t = 0; t < 4; ++t){
        float x = v[t];
        if constexpr (EPI == 1) x = x / (1.f + expf(-x));
        Cs[(rl+t)*BN + cl] = f2bf(x);
      }
    }
  }
  __syncthreads();
  constexpr int TPR = BN*2/16;
  constexpr int RPI = 256 / TPR;
  int rloc = tid / TPR, cb = (tid % TPR)*16;
  #pragma unroll
  for (int r0 = 0; r0 < BM; r0 += RPI){
    int r = r0 + rloc;
    *(float4*)((char*)&Cout[(size_t)(bm*BM + r)*N + bn*BN] + cb) =
      *(const float4*)((const char*)&Cs[r*BN] + cb);
  }
  (void)Cf; (void)gidx; (void)wsel;
}

// ---------------- gemmk64: narrow-N GEMM, BK=64, 48KB LDS (wo + fallback gemm2) ------------
template<int BM, int BN, int EPI>
__global__ __launch_bounds__(256, 3) void gemmk64(const u16* __restrict__ A, const u16* __restrict__ BT,
    u16* __restrict__ Cb, float* __restrict__ Cf, int M, int N, int K,
    const int* __restrict__ gidx, const float* __restrict__ wsel){
  constexpr int WROWS = BM / 2;
  constexpr int WCOLS = BN / 2;
  constexpr int MI = WROWS / 16;
  constexpr int NI = WCOLS / 16;
  constexpr int AR = BM / 32;
  constexpr int BR = BN / 32;
  __shared__ __align__(16) u16 As[2][BM*64];
  __shared__ __align__(16) u16 Bs[2][BN*64];

  int tid = threadIdx.x, wave = tid >> 6, lane = tid & 63;
  int lr = lane & 15, lg = lane >> 4;
  int wm = wave >> 1, wn = wave & 1;

  int lin = blockIdx.x + gridDim.x * blockIdx.y;
  int nwg = gridDim.x * gridDim.y;
  int q8 = nwg >> 3, r8 = nwg & 7;
  int xc = lin & 7, of = lin >> 3;
  int sw = (xc < r8 ? xc*(q8+1) : r8*(q8+1) + (xc-r8)*q8) + of;
  int bm, bn;
  if ((gridDim.x & 15) == 0 && (gridDim.y & 7) == 0){
    int NSM = gridDim.x >> 4;
    int st = sw >> 7, wi = sw & 127;
    bm = (st % NSM)*16 + (wi & 15);
    bn = (st / NSM)*8  + (wi >> 4);
  } else { bm = sw % gridDim.x; bn = sw / gridDim.x; }

  f32x4 zero4 = {0.f,0.f,0.f,0.f};
  f32x4 acc[MI][NI];
  #pragma unroll
  for (int mi = 0; mi < MI; ++mi)
    #pragma unroll
    for (int ni = 0; ni < NI; ++ni) acc[mi][ni] = zero4;

  int srow = wave*8 + (lane >> 3);
  int sgrp = (lane & 7) ^ (lane >> 3);
  const size_t Kb = (size_t)K * 2;
  const char* aptr[AR];
  const char* bptr[BR];
  #pragma unroll
  for (int rr = 0; rr < AR; ++rr)
    aptr[rr] = (const char*)A + (size_t)(bm*BM + rr*32 + srow) * Kb + sgrp*16;
  #pragma unroll
  for (int rr = 0; rr < BR; ++rr)
    bptr[rr] = (const char*)BT + (size_t)(bn*BN + rr*32 + srow) * Kb + sgrp*16;

  int nkt = K >> 6;

#define STAGE64(T, BUF) do { \
    size_t koff = (size_t)(T) << 7; \
    _Pragma("unroll") \
    for (int rr = 0; rr < AR; ++rr) gload16(aptr[rr] + koff, (char*)&As[BUF][0] + rr*4096 + wave*1024); \
    _Pragma("unroll") \
    for (int rr = 0; rr < BR; ++rr) gload16(bptr[rr] + koff, (char*)&Bs[BUF][0] + rr*4096 + wave*1024); \
  } while(0)

  STAGE64(0, 0);
  __syncthreads();

  #pragma unroll 2
  for (int kt = 0; kt < nkt; ++kt){
    int bi = kt & 1;
    if (kt + 1 < nkt) STAGE64(kt+1, bi^1);

    bf16x8 bfrag[NI][2];
    #pragma unroll
    for (int ni = 0; ni < NI; ++ni)
      #pragma unroll
      for (int ks = 0; ks < 2; ++ks){
        int row = wn*WCOLS + ni*16 + lr;
        bfrag[ni][ks] = *(const bf16x8*)&Bs[bi][row*64 + (((ks*4 + lg) ^ (lr & 7))*8)];
      }
    bf16x8 afrag[MI][2];
    #pragma unroll
    for (int mi = 0; mi < MI; ++mi)
      #pragma unroll
      for (int ks = 0; ks < 2; ++ks){
        int row = wm*WROWS + mi*16 + lr;
        afrag[mi][ks] = *(const bf16x8*)&As[bi][row*64 + (((ks*4 + lg) ^ (lr & 7))*8)];
      }
    #pragma unroll
    for (int mi = 0; mi < MI; ++mi)
      #pragma unroll
      for (int ni = 0; ni < NI; ++ni){
        f32x4 a = acc[mi][ni];
        a = mfma16(afrag[mi][0], bfrag[ni][0], a);
        a = mfma16(afrag[mi][1], bfrag[ni][1], a);
        acc[mi][ni] = a;
      }
    __syncthreads();
  }
#undef STAGE64

  #pragma unroll
  for (int mi = 0; mi < MI; ++mi){
    int rb = bm*BM + wm*WROWS + mi*16 + lg*4;
    #pragma unroll
    for (int ni = 0; ni < NI; ++ni){
      int col = bn*BN + wn*WCOLS + ni*16 + lr;
      f32x4 v = acc[mi][ni];
      if constexpr (EPI == 2){
        #pragma unroll
        for (int t = 0; t < 4; ++t) Cf[(size_t)(rb+t)*N + col] += v[t];
      } else {
        #pragma unroll
        for (int t = 0; t < 4; ++t){
          int rr = rb + t;
          int bb = rr >> 10;
          float* hr = Cf + ((size_t)bb*4096 + gidx[rr])*1024;
          hr[col] += v[t] * wsel[rr];
        }
      }
    }
  }
  (void)Cb;
}

// ---------------- flash attention: one q-tile per block, longest-first ----------------
// grid 1024 blocks (4/CU with 40KB LDS -> double the occupancy of the paired 512-block form).
// qt = 15 - (blk>>6): the 16-tile blocks launch first so short blocks backfill behind them.
__global__ __launch_bounds__(256) void attn_k(const u16* __restrict__ qkv, u16* __restrict__ obuf){
  __shared__ u16 Ks[2][4096];
  __shared__ u16 Vt[2][4096];
  __shared__ u16 Pl[4][1024];
  int blk = blockIdx.x;
  int panel = blk & 63;
  int qt = 15 - (blk >> 6);
  int b = panel >> 4, hh = panel & 15;
  int tid = threadIdx.x;
  int wave = tid >> 6, lane = tid & 63;
  int lr = lane & 15, lg = lane >> 4;
  const float SC = 0.125f * 1.44269504f;

  const u16* qrow = qkv + (size_t)(b*1024 + qt*64 + wave*16 + lr)*3072 + hh*64;
  bf16x8 qf0 = *(const bf16x8*)(qrow + lg*8);
  bf16x8 qf1 = *(const bf16x8*)(qrow + 32 + lg*8);

  f32x4 zero4 = {0.f,0.f,0.f,0.f};
  f32x4 oacc[4];
  float m[4], sden[4];
  #pragma unroll
  for (int d = 0; d < 4; ++d) oacc[d] = zero4;
  #pragma unroll
  for (int t = 0; t < 4; ++t){ m[t] = -INFINITY; sden[t] = 0.f; }

  int key0 = tid >> 3,         ce0 = (tid & 7) * 8;
  int key1 = (tid + 256) >> 3, ce1 = ((tid + 256) & 7) * 8;
  u16x8 kreg0, kreg1, vreg0, vreg1;
  const u16* kvbase = qkv + (size_t)(b*1024)*3072 + 1024 + hh*64;
  {
    const u16* g0 = kvbase + (size_t)key0*3072 + ce0;
    const u16* g1 = kvbase + (size_t)key1*3072 + ce1;
    kreg0 = *(const u16x8*)g0;  vreg0 = *(const u16x8*)(g0 + 1024);
    kreg1 = *(const u16x8*)g1;  vreg1 = *(const u16x8*)(g1 + 1024);
  }
  *(u16x8*)&Ks[0][swz16(key0, ce0 >> 3)] = kreg0;
  *(u16x8*)&Ks[0][swz16(key1, ce1 >> 3)] = kreg1;
  #pragma unroll
  for (int j = 0; j < 8; ++j) Vt[0][swze(ce0 + j, key0)] = vreg0[j];
  #pragma unroll
  for (int j = 0; j < 8; ++j) Vt[0][swze(ce1 + j, key1)] = vreg1[j];
  __syncthreads();

  for (int kt = 0; kt <= qt; ++kt){
    int bi = kt & 1;
    if (kt < qt){
      const u16* g0 = kvbase + (size_t)((kt+1)*64 + key0)*3072 + ce0;
      const u16* g1 = kvbase + (size_t)((kt+1)*64 + key1)*3072 + ce1;
      kreg0 = *(const u16x8*)g0;  vreg0 = *(const u16x8*)(g0 + 1024);
      kreg1 = *(const u16x8*)g1;  vreg1 = *(const u16x8*)(g1 + 1024);
    }

    // QK^T
    float sv[4][4];
    #pragma unroll
    for (int kb = 0; kb < 4; ++kb){
      bf16x8 k0f = *(const bf16x8*)&Ks[bi][swz16(kb*16 + lr, lg)];
      bf16x8 k1f = *(const bf16x8*)&Ks[bi][swz16(kb*16 + lr, 4 + lg)];
      f32x4 sa = zero4;
      sa = mfma16(qf0, k0f, sa);
      sa = mfma16(qf1, k1f, sa);
      #pragma unroll
      for (int t = 0; t < 4; ++t) sv[kb][t] = sa[t]*SC;
    }
    if (kt == qt){
      #pragma unroll
      for (int kb = 0; kb < 4; ++kb){
        int keyg = kb*16 + lr;
        #pragma unroll
        for (int t = 0; t < 4; ++t){
          int qg = wave*16 + lg*4 + t;
          if (keyg > qg) sv[kb][t] = -1e30f;
        }
      }
    }
    // online softmax
    float mn[4], scale[4];
    #pragma unroll
    for (int t = 0; t < 4; ++t){
      float tm = fmaxf(fmaxf(sv[0][t], sv[1][t]), fmaxf(sv[2][t], sv[3][t]));
      #pragma unroll
      for (int o = 1; o < 16; o <<= 1) tm = fmaxf(tm, __shfl_xor(tm, o));
      mn[t] = fmaxf(m[t], tm);
      scale[t] = exp2f(m[t] - mn[t]);
      m[t] = mn[t];
    }
    u16* Pw = &Pl[wave][0];
    float ps[4] = {0.f,0.f,0.f,0.f};
    #pragma unroll
    for (int kb = 0; kb < 4; ++kb)
      #pragma unroll
      for (int t = 0; t < 4; ++t){
        float p = exp2f(sv[kb][t] - mn[t]);
        ps[t] += p;
        Pw[swze(lg*4 + t, kb*16 + lr)] = f2bf(p);
      }
    #pragma unroll
    for (int t = 0; t < 4; ++t){
      #pragma unroll
      for (int o = 1; o < 16; o <<= 1) ps[t] += __shfl_xor(ps[t], o);
      sden[t] = sden[t]*scale[t] + ps[t];
    }
    #pragma unroll
    for (int d = 0; d < 4; ++d){
      f32x4 v = oacc[d];
      #pragma unroll
      for (int t = 0; t < 4; ++t) v[t] *= scale[t];
      oacc[d] = v;
    }
    // PV (per-wave private P; lgkm ordering only)
    bf16x8 pa0 = *(const bf16x8*)&Pl[wave][swz16(lr, lg)];
    bf16x8 pa1 = *(const bf16x8*)&Pl[wave][swz16(lr, 4 + lg)];
    #pragma unroll
    for (int d = 0; d < 4; ++d){
      bf16x8 v0 = *(const bf16x8*)&Vt[bi][swz16(d*16 + lr, lg)];
      bf16x8 v1 = *(const bf16x8*)&Vt[bi][swz16(d*16 + lr, 4 + lg)];
      oacc[d] = mfma16(pa0, v0, oacc[d]);
      oacc[d] = mfma16(pa1, v1, oacc[d]);
    }
    // commit next tile into other buffer, then one barrier
    if (kt < qt){
      *(u16x8*)&Ks[bi^1][swz16(key0, ce0 >> 3)] = kreg0;
      *(u16x8*)&Ks[bi^1][swz16(key1, ce1 >> 3)] = kreg1;
      #pragma unroll
      for (int j = 0; j < 8; ++j) Vt[bi^1][swze(ce0 + j, key0)] = vreg0[j];
      #pragma unroll
      for (int j = 0; j < 8; ++j) Vt[bi^1][swze(ce1 + j, key1)] = vreg1[j];
      __syncthreads();
    }
  }

  #pragma unroll
  for (int d = 0; d < 4; ++d)
    #pragma unroll
    for (int t = 0; t < 4; ++t){
      int qrel = qt*64 + wave*16 + lg*4 + t;
      float val = oacc[d][t] / sden[t];
      obuf[(size_t)(b*1024 + qrel)*1024 + hh*64 + d*16 + lr] = f2bf(val);
    }
}

// ---------------- launch ----------------
extern "C" void kernel_launch(void* const* d_in, const int* in_sizes, int n_in,
                              void* d_out, int out_size, void* d_ws, size_t ws_size,
                              hipStream_t stream) {
  const float* hid    = (const float*)d_in[0];
  const float* nssm   = (const float*)d_in[1];
  const float* ssma   = (const float*)d_in[2];
  const float* ssmg   = (const float*)d_in[3];
  const float* routw  = (const float*)d_in[4];
  const float* nattn  = (const float*)d_in[5];
  const float* wq     = (const float*)d_in[6];
  const float* wk     = (const float*)d_in[7];
  const float* wv     = (const float*)d_in[8];
  const float* wo     = (const float*)d_in[9];
  const float* nffn   = (const float*)d_in[10];
  const float* w1     = (const float*)d_in[11];
  const float* w2     = (const float*)d_in[12];

  float* hbuf = (float*)d_out;                 // h lives in d_out [4,4096,1024]
  char* wsb = (char*)d_ws;
  u16*   wqkvT  = (u16*)(wsb + 0);             // [3072][1024] bf16
  u16*   woT    = (u16*)(wsb + 6291456);       // [1024][1024]
  u16*   w1T    = (u16*)(wsb + 8388608);       // [4096][1024]
  u16*   w2T    = (u16*)(wsb + 16777216);      // [1024][4096]
  float* invr   = (float*)(wsb + 25165824);    // [B*S]
  float* scores = (float*)(wsb + 25231360);    // [B*S]
  float* Fc     = (float*)(wsb + 25296896);    // [B,64,1024]
  float* Init   = (float*)(wsb + 26345472);    // [B,64,1024]
  int*   idxb   = (int*)(wsb + 27394048);      // [B,1024]
  float* wselb  = (float*)(wsb + 27410432);    // [B,1024]
  u16*   xn     = (u16*)(wsb + 27426816);      // [4096][1024] bf16
  u16*   qkv    = (u16*)(wsb + 35815424);      // [4096][3072] bf16
  u16*   obuf   = (u16*)(wsb + 60981248);      // [4096][1024] bf16
  u16*   xf     = (u16*)(wsb + 27394048);      // [4096][1024] bf16 (FFN overlay)
  u16*   act    = (u16*)(wsb + 35782656);      // [4096][4096] bf16
  u16*   part   = (u16*)(wsb + 69337088);      // [2][4096][1024] bf16 split-K partials

  transpose_cast<<<dim3(32,32),  256, 0, stream>>>(wq, wqkvT,              1024, 1024);
  transpose_cast<<<dim3(32,32),  256, 0, stream>>>(wk, wqkvT + 1048576,    1024, 1024);
  transpose_cast<<<dim3(32,32),  256, 0, stream>>>(wv, wqkvT + 2097152,    1024, 1024);
  transpose_cast<<<dim3(32,32),  256, 0, stream>>>(wo, woT,                1024, 1024);
  transpose_cast<<<dim3(32,128), 256, 0, stream>>>(w1, w1T,                1024, 4096);
  transpose_cast<<<dim3(128,32), 256, 0, stream>>>(w2, w2T,                4096, 1024);

  rms_inv_k<<<4096, 256, 0, stream>>>(hid, invr);
  ssm_a_k<<<256, 1024, 0, stream>>>(hid, invr, nssm, ssma, Fc);
  ssm_b_k<<<256, 1024, 0, stream>>>(Fc, Init, ssma);
  ssm_c_k<<<256, 1024, 0, stream>>>(hid, invr, nssm, ssma, ssmg, Init, hbuf);

  score_k<<<4096, 256, 0, stream>>>(hbuf, routw, scores);
  aux_k<<<1, 256, 0, stream>>>(scores, hbuf + 16777216);
  topk_k<<<4, 1024, 0, stream>>>(scores, idxb, wselb);

  rownorm_bf16_k<<<1024, 256, 0, stream>>>(hbuf, nattn, xn, idxb, 0);
  gemmk<128,128,0><<<dim3(32,24), 256, 0, stream>>>(xn, wqkvT, qkv, nullptr, 4096, 3072, 1024, nullptr, nullptr);
  attn_k<<<1024, 256, 0, stream>>>(qkv, obuf);
  gemmk64<128,64,3><<<dim3(32,16), 256, 0, stream>>>(obuf, woT, nullptr, hbuf, 4096, 1024, 1024, idxb, wselb);

  bool haveScratch = ws_size >= (size_t)69337088 + 16777216;
  for (int ch = 0; ch < 4; ++ch){
    int m0 = ch * 4096;
    rownorm_bf16_k<<<1024, 256, 0, stream>>>(hbuf, nffn, xf, nullptr, m0);
    gemmk<128,128,1><<<dim3(32,32), 256, 0, stream>>>(xf, w1T, act, nullptr, 4096, 4096, 1024, nullptr, nullptr);
    if (haveScratch){
      gemmks<128,128,0><<<dim3(32,8,2), 256, 0, stream>>>(act, w2T, part, nullptr, 4096, 1024, 2048, 4096, nullptr, nullptr);
      reduce2_k<<<2048, 256, 0, stream>>>(part, hbuf + (size_t)m0*1024);
    } else {
      gemmk64<128,64,2><<<dim3(32,16), 256, 0, stream>>>(act, w2T, nullptr, hbuf + (size_t)m0*1024, 4096, 1024, 4096, nullptr, nullptr);
    }
  }
  (void)in_sizes; (void)n_in; (void)out_size;
}

// Round 21
// 668.370 us; speedup vs baseline: 1.0206x; 1.0206x over previous
//
#include <hip/hip_runtime.h>

typedef unsigned short u16;
typedef unsigned int   u32;
typedef __attribute__((ext_vector_type(4))) float f32x4;
typedef __attribute__((ext_vector_type(8))) __bf16 bf16x8;
typedef __attribute__((ext_vector_type(8))) unsigned short u16x8;

#define DEV __device__ __forceinline__

DEV u16 f2bf(float f){
  u32 u = __builtin_bit_cast(u32, f);
  u32 r = (u + 0x7fffu + ((u >> 16) & 1u)) >> 16;
  return (u16)r;
}
DEV float bf2f(u16 u){ u32 x = ((u32)u) << 16; return __builtin_bit_cast(float, x); }

DEV f32x4 mfma16(bf16x8 a, bf16x8 b, f32x4 c){
  return __builtin_amdgcn_mfma_f32_16x16x32_bf16(a, b, c, 0, 0, 0);
}

DEV void gload16(const void* g, void* l){
  __builtin_amdgcn_global_load_lds((const __attribute__((address_space(1))) u32*)g,
                                   (__attribute__((address_space(3))) u32*)l, 16, 0, 0);
}

// XOR swizzle for [row][64 bf16] LDS tiles (128B row stride), 16B-group granularity.
DEV int swz16(int r, int g){ return r*64 + 8*(g ^ (r&7) ^ ((r>>3)&7)); }
DEV int swze (int r, int e){ return r*64 + (e&7) + 8*(((e>>3) ^ (r&7) ^ ((r>>3)&7))); }

// ---------------- weight transpose + cast: src [R][C] f32 -> dst [C][R] bf16 ----------------
__global__ __launch_bounds__(256) void transpose_cast(const float* __restrict__ src,
                                                      u16* __restrict__ dst, int R, int C){
  __shared__ float tile[32][33];
  int r  = threadIdx.x >> 3;
  int c4 = (threadIdx.x & 7) * 4;
  int r0 = blockIdx.x * 32, c0 = blockIdx.y * 32;
  float4 v = *(const float4*)&src[(size_t)(r0 + r) * C + c0 + c4];
  tile[r][c4+0] = v.x; tile[r][c4+1] = v.y; tile[r][c4+2] = v.z; tile[r][c4+3] = v.w;
  __syncthreads();
  ushort4 o;
  o.x = f2bf(tile[c4+0][r]);
  o.y = f2bf(tile[c4+1][r]);
  o.z = f2bf(tile[c4+2][r]);
  o.w = f2bf(tile[c4+3][r]);
  *(ushort4*)&dst[(size_t)(c0 + r) * R + r0 + c4] = o;
}

// ---------------- inv rms per row (D=1024) ----------------
__global__ __launch_bounds__(256) void rms_inv_k(const float* __restrict__ x, float* __restrict__ inv){
  int row  = blockIdx.x * 4 + (threadIdx.x >> 6);
  int lane = threadIdx.x & 63;
  const float* p = x + (size_t)row * 1024;
  float ss = 0.f;
  #pragma unroll
  for (int j = 0; j < 4; ++j){
    float4 v = *(const float4*)&p[lane*4 + j*256];
    ss += v.x*v.x + v.y*v.y + v.z*v.z + v.w*v.w;
  }
  #pragma unroll
  for (int o = 1; o < 64; o <<= 1) ss += __shfl_xor(ss, o);
  if (lane == 0) inv[row] = 1.f / sqrtf(ss * (1.f/1024.f) + 1e-6f);
}

// ---------------- SSM chunked scan ----------------
__global__ __launch_bounds__(1024) void ssm_a_k(const float* __restrict__ hid, const float* __restrict__ invr,
    const float* __restrict__ nw, const float* __restrict__ av, float* __restrict__ Fc){
  int c = blockIdx.x & 63, b = blockIdx.x >> 6;
  int d = threadIdx.x;
  float w   = nw[d];
  float dec = 1.f/(1.f + expf(-av[d]));
  float od  = 1.f - dec;
  const float* hp = hid + ((size_t)b*4096 + c*64)*1024 + d;
  const float* ip = invr + b*4096 + c*64;
  float hs = 0.f;
  for (int i = 0; i < 64; ++i)
    hs = dec*hs + od*(hp[(size_t)i*1024] * ip[i] * w);
  Fc[((size_t)b*64 + c)*1024 + d] = hs;
}
// parallel chunk-carry scan: wave-level Kogge-Stone over 64 chunks
__global__ __launch_bounds__(1024) void ssm_b_k(const float* __restrict__ Fc, float* __restrict__ Init,
                                                const float* __restrict__ av){
  int b  = blockIdx.x >> 6;
  int dg = blockIdx.x & 63;
  int dl = threadIdx.x >> 6;
  int c  = threadIdx.x & 63;
  int d  = dg*16 + dl;
  float dec = 1.f/(1.f + expf(-av[d]));
  float a = powf(dec, 64.f);
  float x = Fc[((size_t)(b*64 + c))*1024 + d];
  float coef = a;
  #pragma unroll
  for (int s = 1; s < 64; s <<= 1){
    float prev = __shfl_up(x, s, 64);
    if (c >= s) x += coef * prev;
    coef *= coef;
  }
  float ex = __shfl_up(x, 1, 64);
  Init[((size_t)(b*64 + c))*1024 + d] = (c > 0) ? ex : 0.f;
}
__global__ __launch_bounds__(1024) void ssm_c_k(const float* __restrict__ hid, const float* __restrict__ invr,
    const float* __restrict__ nw, const float* __restrict__ av, const float* __restrict__ gn,
    const float* __restrict__ Init, float* __restrict__ hout){
  int c = blockIdx.x & 63, b = blockIdx.x >> 6;
  int d = threadIdx.x;
  float w   = nw[d];
  float g   = gn[d];
  float dec = 1.f/(1.f + expf(-av[d]));
  float od  = 1.f - dec;
  size_t rowoff = ((size_t)b*4096 + c*64)*1024 + d;
  const float* hp = hid + rowoff;
  float* op = hout + rowoff;
  const float* ip = invr + b*4096 + c*64;
  float hs = Init[((size_t)b*64 + c)*1024 + d];
  for (int i = 0; i < 64; ++i){
    float hv = hp[(size_t)i*1024];
    hs = dec*hs + od*(hv * ip[i] * w);
    op[(size_t)i*1024] = hv + hs*g;
  }
}

// ---------------- router scores ----------------
__global__ __launch_bounds__(256) void score_k(const float* __restrict__ h, const float* __restrict__ rw,
                                               float* __restrict__ sc){
  int row  = blockIdx.x * 4 + (threadIdx.x >> 6);
  int lane = threadIdx.x & 63;
  const float* p = h + (size_t)row * 1024;
  float s = 0.f;
  #pragma unroll
  for (int j = 0; j < 4; ++j){
    float4 v = *(const float4*)&p[lane*4 + j*256];
    float4 w = *(const float4*)&rw[lane*4 + j*256];
    s += v.x*w.x + v.y*w.y + v.z*w.z + v.w*w.w;
  }
  #pragma unroll
  for (int o = 1; o < 64; o <<= 1) s += __shfl_xor(s, o);
  if (lane == 0) sc[row] = s;
}

__global__ __launch_bounds__(256) void aux_k(const float* __restrict__ sc, float* __restrict__ out){
  __shared__ float red[256];
  int tid = threadIdx.x;
  float s = 0.f;
  for (int i = tid; i < 16384; i += 256) s += 1.f/(1.f + expf(-sc[i]));
  red[tid] = s; __syncthreads();
  for (int o = 128; o > 0; o >>= 1){ if (tid < o) red[tid] += red[tid+o]; __syncthreads(); }
  if (tid == 0) out[0] = red[0] * (1.f/16384.f);
}

// ---------------- top-k via radix select + stable compaction (per batch) ----------------
__global__ __launch_bounds__(1024) void topk_k(const float* __restrict__ sc, int* __restrict__ idx,
                                               float* __restrict__ wsel){
  __shared__ u32 keys[4096];
  __shared__ int hist[256];
  __shared__ int wsum[16];
  __shared__ int sel_info[2];
  int b = blockIdx.x, tid = threadIdx.x;
  for (int i = tid; i < 4096; i += 1024){
    u32 u = __builtin_bit_cast(u32, sc[b*4096 + i]);
    keys[i] = u ^ ((u32)((int)u >> 31) | 0x80000000u);   // order-preserving map
  }
  int k = 1024;
  u32 prefix = 0, mask = 0;
  for (int level = 3; level >= 0; --level){
    __syncthreads();
    if (tid < 256) hist[tid] = 0;
    __syncthreads();
    int sh = level*8;
    for (int i = tid; i < 4096; i += 1024){
      u32 kk = keys[i];
      if ((kk & mask) == prefix) atomicAdd(&hist[(kk >> sh) & 255], 1);
    }
    __syncthreads();
    if (tid == 0){
      int cum = 0, bb = 255;
      for (; bb > 0; --bb){
        if (cum + hist[bb] >= k) break;
        cum += hist[bb];
      }
      sel_info[0] = bb; sel_info[1] = k - cum;
    }
    __syncthreads();
    prefix |= ((u32)sel_info[0]) << sh;
    mask |= 0xffu << sh;
    k = sel_info[1];
  }
  u32 T = prefix;
  // stable compaction: 4 elements/thread, packed block scan (gt | eq<<13)
  int base = tid*4;
  u32 k4[4]; int cgt = 0, ceq = 0;
  #pragma unroll
  for (int j = 0; j < 4; ++j){
    k4[j] = keys[base+j];
    cgt += (k4[j] > T); ceq += (k4[j] == T);
  }
  int val = cgt | (ceq << 13);
  int incl = val;
  #pragma unroll
  for (int o = 1; o < 64; o <<= 1){ int t = __shfl_up(incl, o, 64); if ((tid&63) >= o) incl += t; }
  int wid = tid >> 6;
  if ((tid&63) == 63) wsum[wid] = incl;
  __syncthreads();
  if (tid < 16){
    int v = wsum[tid];
    #pragma unroll
    for (int o = 1; o < 16; o <<= 1){ int t = __shfl_up(v, o, 64); if (tid >= o) v += t; }
    wsum[tid] = v;
  }
  __syncthreads();
  int excl = incl - val + (wid > 0 ? wsum[wid-1] : 0);
  int g = excl & 0x1fff, e = excl >> 13;
  #pragma unroll
  for (int j = 0; j < 4; ++j){
    bool isgt = (k4[j] > T), iseq = (k4[j] == T);
    if (isgt || (iseq && e < k)){
      int pos = g + (e < k ? e : k);
      idx[b*1024 + pos]  = base + j;
      wsel[b*1024 + pos] = 1.f/(1.f + expf(-sc[b*4096 + base + j]));
    }
    g += isgt; e += iseq;
  }
}

// ---------------- rmsnorm row -> bf16 (optional gather) ----------------
__global__ __launch_bounds__(256) void rownorm_bf16_k(const float* __restrict__ src, const float* __restrict__ w,
    u16* __restrict__ dst, const int* __restrict__ gidx, int base){
  int row  = blockIdx.x * 4 + (threadIdx.x >> 6);
  int lane = threadIdx.x & 63;
  size_t srow;
  if (gidx){ int b = row >> 10; srow = (size_t)b*4096 + gidx[row]; }
  else srow = (size_t)(base + row);
  const float* p = src + srow*1024;
  float4 v[4]; float ss = 0.f;
  #pragma unroll
  for (int j = 0; j < 4; ++j){
    v[j] = *(const float4*)&p[lane*4 + j*256];
    ss += v[j].x*v[j].x + v[j].y*v[j].y + v[j].z*v[j].z + v[j].w*v[j].w;
  }
  #pragma unroll
  for (int o = 1; o < 64; o <<= 1) ss += __shfl_xor(ss, o);
  float inv = 1.f / sqrtf(ss * (1.f/1024.f) + 1e-6f);
  #pragma unroll
  for (int j = 0; j < 4; ++j){
    float4 wv = *(const float4*)&w[lane*4 + j*256];
    ushort4 o4;
    o4.x = f2bf(v[j].x*inv*wv.x);
    o4.y = f2bf(v[j].y*inv*wv.y);
    o4.z = f2bf(v[j].z*inv*wv.z);
    o4.w = f2bf(v[j].w*inv*wv.w);
    *(ushort4*)&dst[(size_t)row*1024 + lane*4 + j*256] = o4;
  }
}

// ---------------- split-K reduce: h += p0 + p1 (bf16 partials, vectorized) ----------------
__global__ __launch_bounds__(256) void reduce2_k(const u16* __restrict__ p, float* __restrict__ h){
  int i = (blockIdx.x*256 + threadIdx.x) * 8;
  u16x8 a = *(const u16x8*)&p[i];
  u16x8 b = *(const u16x8*)&p[4194304 + i];
  #pragma unroll
  for (int j = 0; j < 8; ++j) h[i+j] += bf2f(a[j]) + bf2f(b[j]);
}

// ---------------- gemmk: wide GEMM, m97-exact single-buffer 2-barrier K-loop ----------------
// Experiment: stage -> barrier -> compute -> barrier (no prefetch/double-buffer). m97 measured
// 874 TF / 37% MfmaUtil with this loop at the same tile/BK on this chip; our prefetch variant
// measures 516 TF / 20%. Swizzles, LDS epilogue, supertile decode unchanged.
template<int BM, int BN, int EPI>
__global__ __launch_bounds__(256, 4) void gemmk(const u16* __restrict__ A, const u16* __restrict__ BT,
    u16* __restrict__ Cb, float* __restrict__ Cf, int M, int N, int K,
    const int* __restrict__ gidx, const float* __restrict__ wsel){
  constexpr int WROWS = BM / 2;
  constexpr int WCOLS = BN / 2;
  constexpr int MI = WROWS / 16;
  constexpr int NI = WCOLS / 16;
  constexpr int AR = BM / 64;
  constexpr int BR = BN / 64;
  constexpr int STGB = 64*(BM+BN);      // single buffer: BM*64 + BN*64 bytes
  constexpr int CSB  = BM*BN*2;
  constexpr int SMB  = STGB > CSB ? STGB : CSB;
  __shared__ __align__(16) char smem[SMB];
  u16* As = (u16*)smem;                 // [BM*32]
  u16* Bs = (u16*)(smem + 64*BM);       // [BN*32]

  int tid = threadIdx.x, wave = tid >> 6, lane = tid & 63;
  int lr = lane & 15, lg = lane >> 4;
  int wm = wave >> 1, wn = wave & 1;

  // bijective XCD swizzle, then 16x8 supertile decode
  int lin = blockIdx.x + gridDim.x * blockIdx.y;
  int nwg = gridDim.x * gridDim.y;
  int q8 = nwg >> 3, r8 = nwg & 7;
  int xc = lin & 7, of = lin >> 3;
  int sw = (xc < r8 ? xc*(q8+1) : r8*(q8+1) + (xc-r8)*q8) + of;
  int bm, bn;
  if ((gridDim.x & 15) == 0 && (gridDim.y & 7) == 0){
    int NSM = gridDim.x >> 4;
    int st = sw >> 7, wi = sw & 127;
    bm = (st % NSM)*16 + (wi & 15);
    bn = (st / NSM)*8  + (wi >> 4);
  } else { bm = sw % gridDim.x; bn = sw / gridDim.x; }

  f32x4 zero4 = {0.f,0.f,0.f,0.f};
  f32x4 acc[MI][NI];
  #pragma unroll
  for (int mi = 0; mi < MI; ++mi)
    #pragma unroll
    for (int ni = 0; ni < NI; ++ni) acc[mi][ni] = zero4;

  // staging: LDS[row][g'] = global[row][g' ^ ((row>>1)&3)]
  int srow = wave*16 + (lane >> 2);
  int sgrp = (lane & 3) ^ ((lane >> 3) & 3);
  const size_t Kb = (size_t)K * 2;
  const char* aptr[AR];
  const char* bptr[BR];
  #pragma unroll
  for (int rr = 0; rr < AR; ++rr)
    aptr[rr] = (const char*)A + (size_t)(bm*BM + rr*64 + srow) * Kb + sgrp*16;
  #pragma unroll
  for (int rr = 0; rr < BR; ++rr)
    bptr[rr] = (const char*)BT + (size_t)(bn*BN + rr*64 + srow) * Kb + sgrp*16;

  int nkt = K >> 5;

  for (int kt = 0; kt < nkt; ++kt){
    __syncthreads();   // all waves done reading previous tile (no-op on first iter)
    {
      size_t koff = (size_t)kt << 6;
      #pragma unroll
      for (int rr = 0; rr < AR; ++rr) gload16(aptr[rr] + koff, (char*)As + rr*4096 + wave*1024);
      #pragma unroll
      for (int rr = 0; rr < BR; ++rr) gload16(bptr[rr] + koff, (char*)Bs + rr*4096 + wave*1024);
    }
    __syncthreads();   // implicit vmcnt(0): staged tile visible

    bf16x8 bfrag[NI];
    #pragma unroll
    for (int ni = 0; ni < NI; ++ni){
      int row = wn*WCOLS + ni*16 + lr;
      bfrag[ni] = *(const bf16x8*)&Bs[row*32 + ((lg ^ ((lr>>1) & 3))*8)];
    }
    bf16x8 afrag[MI];
    #pragma unroll
    for (int mi = 0; mi < MI; ++mi){
      int row = wm*WROWS + mi*16 + lr;
      afrag[mi] = *(const bf16x8*)&As[row*32 + ((lg ^ ((lr>>1) & 3))*8)];
    }
    #pragma unroll
    for (int mi = 0; mi < MI; ++mi)
      #pragma unroll
      for (int ni = 0; ni < NI; ++ni)
        acc[mi][ni] = mfma16(afrag[mi], bfrag[ni], acc[mi][ni]);
  }

  __syncthreads();   // last tile's reads complete before smem reuse
  // LDS-staged coalesced epilogue (bf16 outputs)
  u16* Cs = (u16*)smem;
  #pragma unroll
  for (int mi = 0; mi < MI; ++mi){
    int rl = wm*WROWS + mi*16 + lg*4;
    #pragma unroll
    for (int ni = 0; ni < NI; ++ni){
      int cl = wn*WCOLS + ni*16 + lr;
      f32x4 v = acc[mi][ni];
      #pragma unroll
      for (int t = 0; t < 4; ++t){
        float x = v[t];
        if constexpr (EPI == 1) x = x / (1.f + expf(-x));
        Cs[(rl+t)*BN + cl] = f2bf(x);
      }
    }
  }
  __syncthreads();
  constexpr int TPR = BN*2/16;
  constexpr int RPI = 256 / TPR;
  int rloc = tid / TPR, cb = (tid % TPR)*16;
  #pragma unroll
  for (int r0 = 0; r0 < BM; r0 += RPI){
    int r = r0 + rloc;
    *(float4*)((char*)&Cb[(size_t)(bm*BM + r)*N + bn*BN] + cb) =
      *(const float4*)((const char*)&Cs[r*BN] + cb);
  }
  (void)Cf; (void)gidx; (void)wsel;
}

// ---------------- gemmks: split-K wide GEMM (gemm2 slices only; unchanged control) ----------
template<int BM, int BN, int EPI>
__global__ __launch_bounds__(256, 3) void gemmks(const u16* __restrict__ A, const u16* __restrict__ BT,
    u16* __restrict__ Cb, float* __restrict__ Cf, int M, int N, int Ksl, int Kfull,
    const int* __restrict__ gidx, const float* __restrict__ wsel){
  constexpr int WROWS = BM / 2;
  constexpr int WCOLS = BN / 2;
  constexpr int MI = WROWS / 16;
  constexpr int NI = WCOLS / 16;
  constexpr int AR = BM / 64;
  constexpr int BR = BN / 64;
  constexpr int STGB = 128*(BM+BN);
  constexpr int CSB  = BM*BN*2;
  constexpr int SMB  = STGB > CSB ? STGB : CSB;
  __shared__ __align__(16) char smem[SMB];
  u16* As = (u16*)smem;                 // [2][BM*32]
  u16* Bs = (u16*)(smem + 128*BM);      // [2][BN*32]

  int tid = threadIdx.x, wave = tid >> 6, lane = tid & 63;
  int lr = lane & 15, lg = lane >> 4;
  int wm = wave >> 1, wn = wave & 1;

  int lin = blockIdx.x + gridDim.x * blockIdx.y;
  int nwg = gridDim.x * gridDim.y;
  int q8 = nwg >> 3, r8 = nwg & 7;
  int xc = lin & 7, of = lin >> 3;
  int sw = (xc < r8 ? xc*(q8+1) : r8*(q8+1) + (xc-r8)*q8) + of;
  int bm, bn;
  if ((gridDim.x & 15) == 0 && (gridDim.y & 7) == 0){
    int NSM = gridDim.x >> 4;
    int st = sw >> 7, wi = sw & 127;
    bm = (st % NSM)*16 + (wi & 15);
    bn = (st / NSM)*8  + (wi >> 4);
  } else { bm = sw % gridDim.x; bn = sw / gridDim.x; }

  f32x4 zero4 = {0.f,0.f,0.f,0.f};
  f32x4 acc[MI][NI];
  #pragma unroll
  for (int mi = 0; mi < MI; ++mi)
    #pragma unroll
    for (int ni = 0; ni < NI; ++ni) acc[mi][ni] = zero4;

  int srow = wave*16 + (lane >> 2);
  int sgrp = (lane & 3) ^ ((lane >> 3) & 3);
  const size_t Kb = (size_t)Kfull * 2;
  const size_t k0b = (size_t)blockIdx.z * Ksl * 2;
  const char* aptr[AR];
  const char* bptr[BR];
  #pragma unroll
  for (int rr = 0; rr < AR; ++rr)
    aptr[rr] = (const char*)A + (size_t)(bm*BM + rr*64 + srow) * Kb + k0b + sgrp*16;
  #pragma unroll
  for (int rr = 0; rr < BR; ++rr)
    bptr[rr] = (const char*)BT + (size_t)(bn*BN + rr*64 + srow) * Kb + k0b + sgrp*16;

  int nkt = Ksl >> 5;

#define STAGES(T, BUF) do { \
    size_t koff = (size_t)(T) << 6; \
    _Pragma("unroll") \
    for (int rr = 0; rr < AR; ++rr) gload16(aptr[rr] + koff, (char*)As + (BUF)*BM*64 + rr*4096 + wave*1024); \
    _Pragma("unroll") \
    for (int rr = 0; rr < BR; ++rr) gload16(bptr[rr] + koff, (char*)Bs + (BUF)*BN*64 + rr*4096 + wave*1024); \
  } while(0)

  STAGES(0, 0);
  __syncthreads();

  #pragma unroll 2
  for (int kt = 0; kt < nkt; ++kt){
    int bi = kt & 1;
    if (kt + 1 < nkt) STAGES(kt+1, bi^1);

    bf16x8 bfrag[NI];
    #pragma unroll
    for (int ni = 0; ni < NI; ++ni){
      int row = wn*WCOLS + ni*16 + lr;
      bfrag[ni] = *(const bf16x8*)&Bs[bi*BN*32 + row*32 + ((lg ^ ((lr>>1) & 3))*8)];
    }
    bf16x8 afrag[MI];
    #pragma unroll
    for (int mi = 0; mi < MI; ++mi){
      int row = wm*WROWS + mi*16 + lr;
      afrag[mi] = *(const bf16x8*)&As[bi*BM*32 + row*32 + ((lg ^ ((lr>>1) & 3))*8)];
    }
    #pragma unroll
    for (int mi = 0; mi < MI; ++mi)
      #pragma unroll
      for (int ni = 0; ni < NI; ++ni)
        acc[mi][ni] = mfma16(afrag[mi], bfrag[ni], acc[mi][ni]);
    __syncthreads();
  }
#undef STAGES

  u16* Cout = Cb + (size_t)blockIdx.z * M * N;
  u16* Cs = (u16*)smem;
  #pragma unroll
  for (int mi = 0; mi < MI; ++mi){
    int rl = wm*WROWS + mi*16 + lg*4;
    #pragma unroll
    for (int ni = 0; ni < NI; ++ni){
      int cl = wn*WCOLS + ni*16 + lr;
      f32x4 v = acc[mi][ni];
      #pragma unroll
      for (int t = 0; t < 4; ++t){
        float x = v[t];
        if constexpr (EPI == 1) x = x / (1.f + expf(-x));
        Cs[(rl+t)*BN + cl] = f2bf(x);
      }
    }
  }
  __syncthreads();
  constexpr int TPR = BN*2/16;
  constexpr int RPI = 256 / TPR;
  int rloc = tid / TPR, cb = (tid % TPR)*16;
  #pragma unroll
  for (int r0 = 0; r0 < BM; r0 += RPI){
    int r = r0 + rloc;
    *(float4*)((char*)&Cout[(size_t)(bm*BM + r)*N + bn*BN] + cb) =
      *(const float4*)((const char*)&Cs[r*BN] + cb);
  }
  (void)Cf; (void)gidx; (void)wsel;
}

// ---------------- gemmk64: narrow-N GEMM, BK=64, 48KB LDS (wo + fallback gemm2) ------------
template<int BM, int BN, int EPI>
__global__ __launch_bounds__(256, 3) void gemmk64(const u16* __restrict__ A, const u16* __restrict__ BT,
    u16* __restrict__ Cb, float* __restrict__ Cf, int M, int N, int K,
    const int* __restrict__ gidx, const float* __restrict__ wsel){
  constexpr int WROWS = BM / 2;
  constexpr int WCOLS = BN / 2;
  constexpr int MI = WROWS / 16;
  constexpr int NI = WCOLS / 16;
  constexpr int AR = BM / 32;
  constexpr int BR = BN / 32;
  __shared__ __align__(16) u16 As[2][BM*64];
  __shared__ __align__(16) u16 Bs[2][BN*64];

  int tid = threadIdx.x, wave = tid >> 6, lane = tid & 63;
  int lr = lane & 15, lg = lane >> 4;
  int wm = wave >> 1, wn = wave & 1;

  int lin = blockIdx.x + gridDim.x * blockIdx.y;
  int nwg = gridDim.x * gridDim.y;
  int q8 = nwg >> 3, r8 = nwg & 7;
  int xc = lin & 7, of = lin >> 3;
  int sw = (xc < r8 ? xc*(q8+1) : r8*(q8+1) + (xc-r8)*q8) + of;
  int bm, bn;
  if ((gridDim.x & 15) == 0 && (gridDim.y & 7) == 0){
    int NSM = gridDim.x >> 4;
    int st = sw >> 7, wi = sw & 127;
    bm = (st % NSM)*16 + (wi & 15);
    bn = (st / NSM)*8  + (wi >> 4);
  } else { bm = sw % gridDim.x; bn = sw / gridDim.x; }

  f32x4 zero4 = {0.f,0.f,0.f,0.f};
  f32x4 acc[MI][NI];
  #pragma unroll
  for (int mi = 0; mi < MI; ++mi)
    #pragma unroll
    for (int ni = 0; ni < NI; ++ni) acc[mi][ni] = zero4;

  int srow = wave*8 + (lane >> 3);
  int sgrp = (lane & 7) ^ (lane >> 3);
  const size_t Kb = (size_t)K * 2;
  const char* aptr[AR];
  const char* bptr[BR];
  #pragma unroll
  for (int rr = 0; rr < AR; ++rr)
    aptr[rr] = (const char*)A + (size_t)(bm*BM + rr*32 + srow) * Kb + sgrp*16;
  #pragma unroll
  for (int rr = 0; rr < BR; ++rr)
    bptr[rr] = (const char*)BT + (size_t)(bn*BN + rr*32 + srow) * Kb + sgrp*16;

  int nkt = K >> 6;

#define STAGE64(T, BUF) do { \
    size_t koff = (size_t)(T) << 7; \
    _Pragma("unroll") \
    for (int rr = 0; rr < AR; ++rr) gload16(aptr[rr] + koff, (char*)&As[BUF][0] + rr*4096 + wave*1024); \
    _Pragma("unroll") \
    for (int rr = 0; rr < BR; ++rr) gload16(bptr[rr] + koff, (char*)&Bs[BUF][0] + rr*4096 + wave*1024); \
  } while(0)

  STAGE64(0, 0);
  __syncthreads();

  #pragma unroll 2
  for (int kt = 0; kt < nkt; ++kt){
    int bi = kt & 1;
    if (kt + 1 < nkt) STAGE64(kt+1, bi^1);

    bf16x8 bfrag[NI][2];
    #pragma unroll
    for (int ni = 0; ni < NI; ++ni)
      #pragma unroll
      for (int ks = 0; ks < 2; ++ks){
        int row = wn*WCOLS + ni*16 + lr;
        bfrag[ni][ks] = *(const bf16x8*)&Bs[bi][row*64 + (((ks*4 + lg) ^ (lr & 7))*8)];
      }
    bf16x8 afrag[MI][2];
    #pragma unroll
    for (int mi = 0; mi < MI; ++mi)
      #pragma unroll
      for (int ks = 0; ks < 2; ++ks){
        int row = wm*WROWS + mi*16 + lr;
        afrag[mi][ks] = *(const bf16x8*)&As[bi][row*64 + (((ks*4 + lg) ^ (lr & 7))*8)];
      }
    #pragma unroll
    for (int mi = 0; mi < MI; ++mi)
      #pragma unroll
      for (int ni = 0; ni < NI; ++ni){
        f32x4 a = acc[mi][ni];
        a = mfma16(afrag[mi][0], bfrag[ni][0], a);
        a = mfma16(afrag[mi][1], bfrag[ni][1], a);
        acc[mi][ni] = a;
      }
    __syncthreads();
  }
#undef STAGE64

  #pragma unroll
  for (int mi = 0; mi < MI; ++mi){
    int rb = bm*BM + wm*WROWS + mi*16 + lg*4;
    #pragma unroll
    for (int ni = 0; ni < NI; ++ni){
      int col = bn*BN + wn*WCOLS + ni*16 + lr;
      f32x4 v = acc[mi][ni];
      if constexpr (EPI == 2){
        #pragma unroll
        for (int t = 0; t < 4; ++t) Cf[(size_t)(rb+t)*N + col] += v[t];
      } else {
        #pragma unroll
        for (int t = 0; t < 4; ++t){
          int rr = rb + t;
          int bb = rr >> 10;
          float* hr = Cf + ((size_t)bb*4096 + gidx[rr])*1024;
          hr[col] += v[t] * wsel[rr];
        }
      }
    }
  }
  (void)Cb;
}

// ---------------- flash attention: one q-tile per block, longest-first ----------------
__global__ __launch_bounds__(256) void attn_k(const u16* __restrict__ qkv, u16* __restrict__ obuf){
  __shared__ u16 Ks[2][4096];
  __shared__ u16 Vt[2][4096];
  __shared__ u16 Pl[4][1024];
  int blk = blockIdx.x;
  int panel = blk & 63;
  int qt = 15 - (blk >> 6);
  int b = panel >> 4, hh = panel & 15;
  int tid = threadIdx.x;
  int wave = tid >> 6, lane = tid & 63;
  int lr = lane & 15, lg = lane >> 4;
  const float SC = 0.125f * 1.44269504f;

  const u16* qrow = qkv + (size_t)(b*1024 + qt*64 + wave*16 + lr)*3072 + hh*64;
  bf16x8 qf0 = *(const bf16x8*)(qrow + lg*8);
  bf16x8 qf1 = *(const bf16x8*)(qrow + 32 + lg*8);

  f32x4 zero4 = {0.f,0.f,0.f,0.f};
  f32x4 oacc[4];
  float m[4], sden[4];
  #pragma unroll
  for (int d = 0; d < 4; ++d) oacc[d] = zero4;
  #pragma unroll
  for (int t = 0; t < 4; ++t){ m[t] = -INFINITY; sden[t] = 0.f; }

  int key0 = tid >> 3,         ce0 = (tid & 7) * 8;
  int key1 = (tid + 256) >> 3, ce1 = ((tid + 256) & 7) * 8;
  u16x8 kreg0, kreg1, vreg0, vreg1;
  const u16* kvbase = qkv + (size_t)(b*1024)*3072 + 1024 + hh*64;
  {
    const u16* g0 = kvbase + (size_t)key0*3072 + ce0;
    const u16* g1 = kvbase + (size_t)key1*3072 + ce1;
    kreg0 = *(const u16x8*)g0;  vreg0 = *(const u16x8*)(g0 + 1024);
    kreg1 = *(const u16x8*)g1;  vreg1 = *(const u16x8*)(g1 + 1024);
  }
  *(u16x8*)&Ks[0][swz16(key0, ce0 >> 3)] = kreg0;
  *(u16x8*)&Ks[0][swz16(key1, ce1 >> 3)] = kreg1;
  #pragma unroll
  for (int j = 0; j < 8; ++j) Vt[0][swze(ce0 + j, key0)] = vreg0[j];
  #pragma unroll
  for (int j = 0; j < 8; ++j) Vt[0][swze(ce1 + j, key1)] = vreg1[j];
  __syncthreads();

  for (int kt = 0; kt <= qt; ++kt){
    int bi = kt & 1;
    if (kt < qt){
      const u16* g0 = kvbase + (size_t)((kt+1)*64 + key0)*3072 + ce0;
      const u16* g1 = kvbase + (size_t)((kt+1)*64 + key1)*3072 + ce1;
      kreg0 = *(const u16x8*)g0;  vreg0 = *(const u16x8*)(g0 + 1024);
      kreg1 = *(const u16x8*)g1;  vreg1 = *(const u16x8*)(g1 + 1024);
    }

    float sv[4][4];
    #pragma unroll
    for (int kb = 0; kb < 4; ++kb){
      bf16x8 k0f = *(const bf16x8*)&Ks[bi][swz16(kb*16 + lr, lg)];
      bf16x8 k1f = *(const bf16x8*)&Ks[bi][swz16(kb*16 + lr, 4 + lg)];
      f32x4 sa = zero4;
      sa = mfma16(qf0, k0f, sa);
      sa = mfma16(qf1, k1f, sa);
      #pragma unroll
      for (int t = 0; t < 4; ++t) sv[kb][t] = sa[t]*SC;
    }
    if (kt == qt){
      #pragma unroll
      for (int kb = 0; kb < 4; ++kb){
        int keyg = kb*16 + lr;
        #pragma unroll
        for (int t = 0; t < 4; ++t){
          int qg = wave*16 + lg*4 + t;
          if (keyg > qg) sv[kb][t] = -1e30f;
        }
      }
    }
    float mn[4], scale[4];
    #pragma unroll
    for (int t = 0; t < 4; ++t){
      float tm = fmaxf(fmaxf(sv[0][t], sv[1][t]), fmaxf(sv[2][t], sv[3][t]));
      #pragma unroll
      for (int o = 1; o < 16; o <<= 1) tm = fmaxf(tm, __shfl_xor(tm, o));
      mn[t] = fmaxf(m[t], tm);
      scale[t] = exp2f(m[t] - mn[t]);
      m[t] = mn[t];
    }
    u16* Pw = &Pl[wave][0];
    float ps[4] = {0.f,0.f,0.f,0.f};
    #pragma unroll
    for (int kb = 0; kb < 4; ++kb)
      #pragma unroll
      for (int t = 0; t < 4; ++t){
        float p = exp2f(sv[kb][t] - mn[t]);
        ps[t] += p;
        Pw[swze(lg*4 + t, kb*16 + lr)] = f2bf(p);
      }
    #pragma unroll
    for (int t = 0; t < 4; ++t){
      #pragma unroll
      for (int o = 1; o < 16; o <<= 1) ps[t] += __shfl_xor(ps[t], o);
      sden[t] = sden[t]*scale[t] + ps[t];
    }
    #pragma unroll
    for (int d = 0; d < 4; ++d){
      f32x4 v = oacc[d];
      #pragma unroll
      for (int t = 0; t < 4; ++t) v[t] *= scale[t];
      oacc[d] = v;
    }
    bf16x8 pa0 = *(const bf16x8*)&Pl[wave][swz16(lr, lg)];
    bf16x8 pa1 = *(const bf16x8*)&Pl[wave][swz16(lr, 4 + lg)];
    #pragma unroll
    for (int d = 0; d < 4; ++d){
      bf16x8 v0 = *(const bf16x8*)&Vt[bi][swz16(d*16 + lr, lg)];
      bf16x8 v1 = *(const bf16x8*)&Vt[bi][swz16(d*16 + lr, 4 + lg)];
      oacc[d] = mfma16(pa0, v0, oacc[d]);
      oacc[d] = mfma16(pa1, v1, oacc[d]);
    }
    if (kt < qt){
      *(u16x8*)&Ks[bi^1][swz16(key0, ce0 >> 3)] = kreg0;
      *(u16x8*)&Ks[bi^1][swz16(key1, ce1 >> 3)] = kreg1;
      #pragma unroll
      for (int j = 0; j < 8; ++j) Vt[bi^1][swze(ce0 + j, key0)] = vreg0[j];
      #pragma unroll
      for (int j = 0; j < 8; ++j) Vt[bi^1][swze(ce1 + j, key1)] = vreg1[j];
      __syncthreads();
    }
  }

  #pragma unroll
  for (int d = 0; d < 4; ++d)
    #pragma unroll
    for (int t = 0; t < 4; ++t){
      int qrel = qt*64 + wave*16 + lg*4 + t;
      float val = oacc[d][t] / sden[t];
      obuf[(size_t)(b*1024 + qrel)*1024 + hh*64 + d*16 + lr] = f2bf(val);
    }
}

// ---------------- launch ----------------
extern "C" void kernel_launch(void* const* d_in, const int* in_sizes, int n_in,
                              void* d_out, int out_size, void* d_ws, size_t ws_size,
                              hipStream_t stream) {
  const float* hid    = (const float*)d_in[0];
  const float* nssm   = (const float*)d_in[1];
  const float* ssma   = (const float*)d_in[2];
  const float* ssmg   = (const float*)d_in[3];
  const float* routw  = (const float*)d_in[4];
  const float* nattn  = (const float*)d_in[5];
  const float* wq     = (const float*)d_in[6];
  const float* wk     = (const float*)d_in[7];
  const float* wv     = (const float*)d_in[8];
  const float* wo     = (const float*)d_in[9];
  const float* nffn   = (const float*)d_in[10];
  const float* w1     = (const float*)d_in[11];
  const float* w2     = (const float*)d_in[12];

  float* hbuf = (float*)d_out;                 // h lives in d_out [4,4096,1024]
  char* wsb = (char*)d_ws;
  u16*   wqkvT  = (u16*)(wsb + 0);             // [3072][1024] bf16
  u16*   woT    = (u16*)(wsb + 6291456);       // [1024][1024]
  u16*   w1T    = (u16*)(wsb + 8388608);       // [4096][1024]
  u16*   w2T    = (u16*)(wsb + 16777216);      // [1024][4096]
  float* invr   = (float*)(wsb + 25165824);    // [B*S]
  float* scores = (float*)(wsb + 25231360);    // [B*S]
  float* Fc     = (float*)(wsb + 25296896);    // [B,64,1024]
  float* Init   = (float*)(wsb + 26345472);    // [B,64,1024]
  int*   idxb   = (int*)(wsb + 27394048);      // [B,1024]
  float* wselb  = (float*)(wsb + 27410432);    // [B,1024]
  u16*   xn     = (u16*)(wsb + 27426816);      // [4096][1024] bf16
  u16*   qkv    = (u16*)(wsb + 35815424);      // [4096][3072] bf16
  u16*   obuf   = (u16*)(wsb + 60981248);      // [4096][1024] bf16
  u16*   xf     = (u16*)(wsb + 27394048);      // [4096][1024] bf16 (FFN overlay)
  u16*   act    = (u16*)(wsb + 35782656);      // [4096][4096] bf16
  u16*   part   = (u16*)(wsb + 69337088);      // [2][4096][1024] bf16 split-K partials

  transpose_cast<<<dim3(32,32),  256, 0, stream>>>(wq, wqkvT,              1024, 1024);
  transpose_cast<<<dim3(32,32),  256, 0, stream>>>(wk, wqkvT + 1048576,    1024, 1024);
  transpose_cast<<<dim3(32,32),  256, 0, stream>>>(wv, wqkvT + 2097152,    1024, 1024);
  transpose_cast<<<dim3(32,32),  256, 0, stream>>>(wo, woT,                1024, 1024);
  transpose_cast<<<dim3(32,128), 256, 0, stream>>>(w1, w1T,                1024, 4096);
  transpose_cast<<<dim3(128,32), 256, 0, stream>>>(w2, w2T,                4096, 1024);

  rms_inv_k<<<4096, 256, 0, stream>>>(hid, invr);
  ssm_a_k<<<256, 1024, 0, stream>>>(hid, invr, nssm, ssma, Fc);
  ssm_b_k<<<256, 1024, 0, stream>>>(Fc, Init, ssma);
  ssm_c_k<<<256, 1024, 0, stream>>>(hid, invr, nssm, ssma, ssmg, Init, hbuf);

  score_k<<<4096, 256, 0, stream>>>(hbuf, routw, scores);
  aux_k<<<1, 256, 0, stream>>>(scores, hbuf + 16777216);
  topk_k<<<4, 1024, 0, stream>>>(scores, idxb, wselb);

  rownorm_bf16_k<<<1024, 256, 0, stream>>>(hbuf, nattn, xn, idxb, 0);
  gemmk<128,128,0><<<dim3(32,24), 256, 0, stream>>>(xn, wqkvT, qkv, nullptr, 4096, 3072, 1024, nullptr, nullptr);
  attn_k<<<1024, 256, 0, stream>>>(qkv, obuf);
  gemmk64<128,64,3><<<dim3(32,16), 256, 0, stream>>>(obuf, woT, nullptr, hbuf, 4096, 1024, 1024, idxb, wselb);

  bool haveScratch = ws_size >= (size_t)69337088 + 16777216;
  for (int ch = 0; ch < 4; ++ch){
    int m0 = ch * 4096;
    rownorm_bf16_k<<<1024, 256, 0, stream>>>(hbuf, nffn, xf, nullptr, m0);
    gemmk<128,128,1><<<dim3(32,32), 256, 0, stream>>>(xf, w1T, act, nullptr, 4096, 4096, 1024, nullptr, nullptr);
    if (haveScratch){
      gemmks<128,128,0><<<dim3(32,8,2), 256, 0, stream>>>(act, w2T, part, nullptr, 4096, 1024, 2048, 4096, nullptr, nullptr);
      reduce2_k<<<2048, 256, 0, stream>>>(part, hbuf + (size_t)m0*1024);
    } else {
      gemmk64<128,64,2><<<dim3(32,16), 256, 0, stream>>>(act, w2T, nullptr, hbuf + (size_t)m0*1024, 4096, 1024, 4096, nullptr, nullptr);
    }
  }
  (void)in_sizes; (void)n_in; (void)out_size;
}